// Round 2
// baseline (205.040 us; speedup 1.0000x reference)
//
#include <hip/hip_runtime.h>
#include <math.h>

// Problem constants (B,T,H,W,D) = (8,32,16,16,128)
#define Bn 8
#define Tn 32
#define Hn 16
#define Wn 16
#define Dn 128
#define HWD (Hn * Wn * Dn)      // 32768 floats between consecutive t
#define LSTR 132                // LDS row stride (pad 128 -> 132 to break bank aliasing)
#define EPSV 1e-5f

__device__ __forceinline__ void fma4(float4& acc, float s, const float4& m) {
    acc.x = fmaf(s, m.x, acc.x);
    acc.y = fmaf(s, m.y, acc.y);
    acc.z = fmaf(s, m.z, acc.z);
    acc.w = fmaf(s, m.w, acc.w);
}

__launch_bounds__(256, 2)
__global__ void gmamba_fused(const float* __restrict__ x,
                             const float* __restrict__ g1, const float* __restrict__ b1,
                             const float* __restrict__ g2, const float* __restrict__ b2,
                             const float* __restrict__ WB, const float* __restrict__ bB,
                             const float* __restrict__ WC, const float* __restrict__ bC,
                             const float* __restrict__ Wo, const float* __restrict__ bo,
                             const float* __restrict__ A,
                             float* __restrict__ out)
{
    __shared__ float d_lds[Tn][LSTR];   // d_seq rows (kept for final residual)
    __shared__ float xn_lds[Tn][LSTR];  // LN2(LN1(d_seq))
    __shared__ float bt_lds[Tn][LSTR];  // Bt, later overwritten with y = Ct*h
    __shared__ float ct_lds[Tn][LSTR];  // Ct

    const int tid = threadIdx.x;
    const int s   = blockIdx.x;          // 0..2047  == (b, h*W+w)
    const int b   = s >> 8;              // H*W = 256
    const int hw  = s & 255;
    const size_t base = (size_t)b * Tn * HWD + (size_t)hw * Dn;

    // ================= Phase 1: d_seq + LN1 + LN2 -> xn =================
    // 8 threads per row (t), 16 contiguous channels per thread.
    {
        const int row = tid >> 3;        // t in 0..31
        const int sub = tid & 7;
        const int c0  = sub * 16;

        float d[16];
        {
            const float* xr = x + base + (size_t)row * HWD + c0;
            float4 a0 = *(const float4*)(xr + 0);
            float4 a1 = *(const float4*)(xr + 4);
            float4 a2 = *(const float4*)(xr + 8);
            float4 a3 = *(const float4*)(xr + 12);
            if (row > 0) {
                const float* xp = xr - HWD;
                float4 p0 = *(const float4*)(xp + 0);
                float4 p1 = *(const float4*)(xp + 4);
                float4 p2 = *(const float4*)(xp + 8);
                float4 p3 = *(const float4*)(xp + 12);
                d[0]=a0.x-p0.x; d[1]=a0.y-p0.y; d[2]=a0.z-p0.z; d[3]=a0.w-p0.w;
                d[4]=a1.x-p1.x; d[5]=a1.y-p1.y; d[6]=a1.z-p1.z; d[7]=a1.w-p1.w;
                d[8]=a2.x-p2.x; d[9]=a2.y-p2.y; d[10]=a2.z-p2.z; d[11]=a2.w-p2.w;
                d[12]=a3.x-p3.x; d[13]=a3.y-p3.y; d[14]=a3.z-p3.z; d[15]=a3.w-p3.w;
            } else {
                #pragma unroll
                for (int i = 0; i < 16; ++i) d[i] = 0.f;
            }
        }

        // store d_seq to LDS (needed for residual at the end)
        #pragma unroll
        for (int i = 0; i < 16; i += 4) {
            *(float4*)(&d_lds[row][c0 + i]) = make_float4(d[i], d[i+1], d[i+2], d[i+3]);
        }

        // LN1 statistics over the row (reduce across the 8 lanes of this row)
        float sum = 0.f, ss = 0.f;
        #pragma unroll
        for (int i = 0; i < 16; ++i) { sum += d[i]; ss += d[i] * d[i]; }
        #pragma unroll
        for (int m = 1; m < 8; m <<= 1) {
            sum += __shfl_xor(sum, m);
            ss  += __shfl_xor(ss,  m);
        }
        float mu1 = sum * (1.f / 128.f);
        float var1 = ss * (1.f / 128.f) - mu1 * mu1;
        float rs1 = rsqrtf(var1 + EPSV);

        // dn = (d-mu1)*rs1*g1 + b1  (params loaded per-thread for its 16 channels)
        float dn[16];
        {
            float4 ga[4], bb4[4];
            #pragma unroll
            for (int i = 0; i < 4; ++i) {
                ga[i]  = *(const float4*)(g1 + c0 + 4 * i);
                bb4[i] = *(const float4*)(b1 + c0 + 4 * i);
            }
            #pragma unroll
            for (int i = 0; i < 4; ++i) {
                dn[4*i+0] = fmaf((d[4*i+0] - mu1) * rs1, ga[i].x, bb4[i].x);
                dn[4*i+1] = fmaf((d[4*i+1] - mu1) * rs1, ga[i].y, bb4[i].y);
                dn[4*i+2] = fmaf((d[4*i+2] - mu1) * rs1, ga[i].z, bb4[i].z);
                dn[4*i+3] = fmaf((d[4*i+3] - mu1) * rs1, ga[i].w, bb4[i].w);
            }
        }

        // LN2 statistics
        float sum2 = 0.f, ss2 = 0.f;
        #pragma unroll
        for (int i = 0; i < 16; ++i) { sum2 += dn[i]; ss2 += dn[i] * dn[i]; }
        #pragma unroll
        for (int m = 1; m < 8; m <<= 1) {
            sum2 += __shfl_xor(sum2, m);
            ss2  += __shfl_xor(ss2,  m);
        }
        float mu2 = sum2 * (1.f / 128.f);
        float var2 = ss2 * (1.f / 128.f) - mu2 * mu2;
        float rs2 = rsqrtf(var2 + EPSV);

        {
            float4 ga[4], bb4[4];
            #pragma unroll
            for (int i = 0; i < 4; ++i) {
                ga[i]  = *(const float4*)(g2 + c0 + 4 * i);
                bb4[i] = *(const float4*)(b2 + c0 + 4 * i);
            }
            #pragma unroll
            for (int i = 0; i < 4; ++i) {
                float4 v;
                v.x = fmaf((dn[4*i+0] - mu2) * rs2, ga[i].x, bb4[i].x);
                v.y = fmaf((dn[4*i+1] - mu2) * rs2, ga[i].y, bb4[i].y);
                v.z = fmaf((dn[4*i+2] - mu2) * rs2, ga[i].z, bb4[i].z);
                v.w = fmaf((dn[4*i+3] - mu2) * rs2, ga[i].w, bb4[i].w);
                *(float4*)(&xn_lds[row][c0 + 4 * i]) = v;
            }
        }
    }
    __syncthreads();

    // ================= Phase 2: Bt = xn@WB + bB ; Ct = xn@WC + bC =================
    // Thread tile: 4 rows x 4 cols, 8 row-groups x 32 col-groups.
    const int rg = tid >> 5;            // 0..7
    const int cg = tid & 31;            // 0..31
    const int r0 = rg * 4;
    const int cc = cg * 4;

    {
        float4 aB[4], aC[4];
        float4 biasB = *(const float4*)(bB + cc);
        float4 biasC = *(const float4*)(bC + cc);
        #pragma unroll
        for (int i = 0; i < 4; ++i) { aB[i] = biasB; aC[i] = biasC; }

        #pragma unroll 4
        for (int k0 = 0; k0 < Dn; k0 += 4) {
            float4 wbv[4], wcv[4];
            #pragma unroll
            for (int kk = 0; kk < 4; ++kk) {
                wbv[kk] = *(const float4*)(WB + (size_t)(k0 + kk) * Dn + cc);
                wcv[kk] = *(const float4*)(WC + (size_t)(k0 + kk) * Dn + cc);
            }
            #pragma unroll
            for (int i = 0; i < 4; ++i) {
                float4 xv = *(const float4*)(&xn_lds[r0 + i][k0]);
                fma4(aB[i], xv.x, wbv[0]); fma4(aB[i], xv.y, wbv[1]);
                fma4(aB[i], xv.z, wbv[2]); fma4(aB[i], xv.w, wbv[3]);
                fma4(aC[i], xv.x, wcv[0]); fma4(aC[i], xv.y, wcv[1]);
                fma4(aC[i], xv.z, wcv[2]); fma4(aC[i], xv.w, wcv[3]);
            }
        }
        #pragma unroll
        for (int i = 0; i < 4; ++i) {
            *(float4*)(&bt_lds[r0 + i][cc]) = aB[i];
            *(float4*)(&ct_lds[r0 + i][cc]) = aC[i];
        }
    }
    __syncthreads();

    // ================= Phase 3: diagonal scan, y = Ct * h (overwrite bt_lds) =====
    if (tid < Dn) {
        const int c = tid;
        const float dec = expf(A[c]);
        float h = 0.f;
        #pragma unroll
        for (int t = 0; t < Tn; ++t) {
            h = fmaf(dec, h, bt_lds[t][c]);
            bt_lds[t][c] = ct_lds[t][c] * h;
        }
    }
    __syncthreads();

    // ================= Phase 4: out = y@Wo + bo + d_seq =================
    {
        float4 aO[4];
        float4 biasO = *(const float4*)(bo + cc);
        #pragma unroll
        for (int i = 0; i < 4; ++i) aO[i] = biasO;

        #pragma unroll 4
        for (int k0 = 0; k0 < Dn; k0 += 4) {
            float4 wov[4];
            #pragma unroll
            for (int kk = 0; kk < 4; ++kk)
                wov[kk] = *(const float4*)(Wo + (size_t)(k0 + kk) * Dn + cc);
            #pragma unroll
            for (int i = 0; i < 4; ++i) {
                float4 yv = *(const float4*)(&bt_lds[r0 + i][k0]);
                fma4(aO[i], yv.x, wov[0]); fma4(aO[i], yv.y, wov[1]);
                fma4(aO[i], yv.z, wov[2]); fma4(aO[i], yv.w, wov[3]);
            }
        }

        #pragma unroll
        for (int i = 0; i < 4; ++i) {
            const int r = r0 + i;
            float4 dd = *(const float4*)(&d_lds[r][cc]);
            aO[i].x += dd.x; aO[i].y += dd.y; aO[i].z += dd.z; aO[i].w += dd.w;
            *(float4*)(out + base + (size_t)r * HWD + cc) = aO[i];
        }
    }
}

extern "C" void kernel_launch(void* const* d_in, const int* in_sizes, int n_in,
                              void* d_out, int out_size, void* d_ws, size_t ws_size,
                              hipStream_t stream) {
    const float* x  = (const float*)d_in[0];
    const float* g1 = (const float*)d_in[1];
    const float* b1 = (const float*)d_in[2];
    const float* g2 = (const float*)d_in[3];
    const float* b2 = (const float*)d_in[4];
    const float* WB = (const float*)d_in[5];
    const float* bB = (const float*)d_in[6];
    const float* WC = (const float*)d_in[7];
    const float* bC = (const float*)d_in[8];
    const float* Wo = (const float*)d_in[9];
    const float* bo = (const float*)d_in[10];
    const float* A  = (const float*)d_in[11];
    float* out = (float*)d_out;

    dim3 grid(Bn * Hn * Wn);   // 2048 blocks: one per (b,h,w)
    dim3 block(256);
    hipLaunchKernelGGL(gmamba_fused, grid, block, 0, stream,
                       x, g1, b1, g2, b2, WB, bB, WC, bC, Wo, bo, A, out);
}

// Round 7
// 139.436 us; speedup vs baseline: 1.4705x; 1.4705x over previous
//
#include <hip/hip_runtime.h>
#include <math.h>

// Problem constants (B,T,H,W,D) = (8,32,16,16,128)
#define Bn 8
#define Tn 32
#define Hn 16
#define Wn 16
#define Dn 128
#define HWD (Hn * Wn * Dn)      // 32768 floats between consecutive t
#define LSTR 132                // fp32 LDS row stride
#define HSTR 136                // bf16 LDS row stride (136*2B = 272B = 17*16B)
#define EPSV 1e-5f

typedef __bf16 bf16x8 __attribute__((ext_vector_type(8)));
typedef float f32x4 __attribute__((ext_vector_type(4)));
typedef unsigned short ushort8 __attribute__((ext_vector_type(8)));
typedef unsigned short ushort_t;

__device__ __forceinline__ ushort_t bf16_rne(float f) {
    unsigned u = __builtin_bit_cast(unsigned, f);
    unsigned r = u + 0x7FFFu + ((u >> 16) & 1u);
    return (ushort_t)(r >> 16);
}
__device__ __forceinline__ float bf16_to_f32(ushort_t h) {
    return __builtin_bit_cast(float, (unsigned)h << 16);
}

// ===================== Pre-pass: weights -> MFMA B-fragment layout ==========
// ws layout (ushort units): frag index = w*64 + half*32 + kt*8 + nt; frag =
// 512 ushorts; element j of lane l = W[kt*32 + (l>>4)*8 + j][nt*16 + (l&15)],
// hi (half=0) or lo (half=1) bf16 limb.  w - whi - wlo error <= 2^-16 |w|.
__global__ void prep_weights(const float* __restrict__ WB,
                             const float* __restrict__ WC,
                             const float* __restrict__ Wo,
                             ushort_t* __restrict__ ws)
{
    const int tg = blockIdx.x * 256 + threadIdx.x;   // 0..6143
    const int l  = tg & 63;
    const int f  = tg >> 6;                          // 0..95 = (w, kt, nt)
    const int nt = f & 7;
    const int kt = (f >> 3) & 3;
    const int w  = f >> 5;                           // 0,1,2
    const float* W = (w == 0) ? WB : (w == 1) ? WC : Wo;

    const int row0 = kt * 32 + (l >> 4) * 8;
    const int col  = nt * 16 + (l & 15);

    ushort_t hi[8], lo[8];
    #pragma unroll
    for (int j = 0; j < 8; ++j) {
        float v = W[(size_t)(row0 + j) * Dn + col];
        ushort_t h = bf16_rne(v);
        hi[j] = h;
        lo[j] = bf16_rne(v - bf16_to_f32(h));
    }
    ushort8 vh = {hi[0],hi[1],hi[2],hi[3],hi[4],hi[5],hi[6],hi[7]};
    ushort8 vl = {lo[0],lo[1],lo[2],lo[3],lo[4],lo[5],lo[6],lo[7]};
    size_t hioff = ((size_t)(w * 64 + kt * 8 + nt)) * 512 + (size_t)l * 8;
    size_t looff = ((size_t)(w * 64 + 32 + kt * 8 + nt)) * 512 + (size_t)l * 8;
    *(ushort8*)(ws + hioff) = vh;
    *(ushort8*)(ws + looff) = vl;
}

// ===================== Main fused kernel ====================================
__launch_bounds__(256, 2)
__global__ void gmamba_fused(const float* __restrict__ x,
                             const float* __restrict__ g1, const float* __restrict__ b1,
                             const float* __restrict__ g2, const float* __restrict__ b2,
                             const float* __restrict__ bB,
                             const float* __restrict__ bC,
                             const float* __restrict__ bo,
                             const float* __restrict__ A,
                             const ushort_t* __restrict__ ws,
                             float* __restrict__ out)
{
    __shared__ float d_lds[Tn][LSTR];                    // d_seq (residual)
    __shared__ float bt_lds[Tn][LSTR];                   // Bt (scan input)
    __shared__ float ct_lds[Tn][LSTR];                   // Ct (gate)
    __shared__ __align__(16) ushort_t xn_hi[Tn][HSTR];   // xn hi limb, later y1
    __shared__ __align__(16) ushort_t xn_lo[Tn][HSTR];   // xn lo limb, later y2
    __shared__ __align__(16) ushort_t y3_lds[Tn][HSTR];  // y third limb

    const int tid = threadIdx.x;
    const int s   = blockIdx.x;          // (b, h*W+w)
    const int b   = s >> 8;
    const int hw  = s & 255;
    const size_t base = (size_t)b * Tn * HWD + (size_t)hw * Dn;

    // ============ Phase 1: d_seq + LN1 + LN2 -> xn (bf16 hi/lo in LDS) ======
    {
        const int row = tid >> 3;        // t
        const int sub = tid & 7;
        const int c0  = sub * 16;

        float d[16];
        {
            const float* xr = x + base + (size_t)row * HWD + c0;
            float4 a0 = *(const float4*)(xr + 0);
            float4 a1 = *(const float4*)(xr + 4);
            float4 a2 = *(const float4*)(xr + 8);
            float4 a3 = *(const float4*)(xr + 12);
            if (row > 0) {
                const float* xp = xr - HWD;
                float4 p0 = *(const float4*)(xp + 0);
                float4 p1 = *(const float4*)(xp + 4);
                float4 p2 = *(const float4*)(xp + 8);
                float4 p3 = *(const float4*)(xp + 12);
                d[0]=a0.x-p0.x; d[1]=a0.y-p0.y; d[2]=a0.z-p0.z; d[3]=a0.w-p0.w;
                d[4]=a1.x-p1.x; d[5]=a1.y-p1.y; d[6]=a1.z-p1.z; d[7]=a1.w-p1.w;
                d[8]=a2.x-p2.x; d[9]=a2.y-p2.y; d[10]=a2.z-p2.z; d[11]=a2.w-p2.w;
                d[12]=a3.x-p3.x; d[13]=a3.y-p3.y; d[14]=a3.z-p3.z; d[15]=a3.w-p3.w;
            } else {
                #pragma unroll
                for (int i = 0; i < 16; ++i) d[i] = 0.f;
            }
        }

        #pragma unroll
        for (int i = 0; i < 16; i += 4)
            *(float4*)(&d_lds[row][c0 + i]) = make_float4(d[i], d[i+1], d[i+2], d[i+3]);

        float sum = 0.f, ss = 0.f;
        #pragma unroll
        for (int i = 0; i < 16; ++i) { sum += d[i]; ss += d[i] * d[i]; }
        #pragma unroll
        for (int m = 1; m < 8; m <<= 1) {
            sum += __shfl_xor(sum, m);
            ss  += __shfl_xor(ss,  m);
        }
        float mu1 = sum * (1.f / 128.f);
        float rs1 = rsqrtf(ss * (1.f / 128.f) - mu1 * mu1 + EPSV);

        float dn[16];
        #pragma unroll
        for (int i = 0; i < 16; ++i)
            dn[i] = fmaf((d[i] - mu1) * rs1, g1[c0 + i], b1[c0 + i]);

        float sum2 = 0.f, ss2 = 0.f;
        #pragma unroll
        for (int i = 0; i < 16; ++i) { sum2 += dn[i]; ss2 += dn[i] * dn[i]; }
        #pragma unroll
        for (int m = 1; m < 8; m <<= 1) {
            sum2 += __shfl_xor(sum2, m);
            ss2  += __shfl_xor(ss2,  m);
        }
        float mu2 = sum2 * (1.f / 128.f);
        float rs2 = rsqrtf(ss2 * (1.f / 128.f) - mu2 * mu2 + EPSV);

        ushort_t hi[16], lo[16];
        #pragma unroll
        for (int i = 0; i < 16; ++i) {
            float v = fmaf((dn[i] - mu2) * rs2, g2[c0 + i], b2[c0 + i]);
            ushort_t h = bf16_rne(v);
            hi[i] = h;
            lo[i] = bf16_rne(v - bf16_to_f32(h));
        }
        ushort8 h0 = {hi[0],hi[1],hi[2],hi[3],hi[4],hi[5],hi[6],hi[7]};
        ushort8 h1 = {hi[8],hi[9],hi[10],hi[11],hi[12],hi[13],hi[14],hi[15]};
        ushort8 l0 = {lo[0],lo[1],lo[2],lo[3],lo[4],lo[5],lo[6],lo[7]};
        ushort8 l1 = {lo[8],lo[9],lo[10],lo[11],lo[12],lo[13],lo[14],lo[15]};
        *(ushort8*)(&xn_hi[row][c0])     = h0;
        *(ushort8*)(&xn_hi[row][c0 + 8]) = h1;
        *(ushort8*)(&xn_lo[row][c0])     = l0;
        *(ushort8*)(&xn_lo[row][c0 + 8]) = l1;
    }
    __syncthreads();

    const int wv = tid >> 6;     // wave 0..3
    const int l  = tid & 63;
    const int lr = l & 15;       // A-row / B-col / C-col
    const int lg = l >> 4;       // k-group; C row-group

    // ============ Phase 2: Bt = xn@WB + bB ; Ct = xn@WC + bC (MFMA, 4-term) =
    // wave 0: WB ntiles 0-3; wave 1: WB 4-7; wave 2: WC 0-3; wave 3: WC 4-7.
    {
        const int gemm = wv >> 1;
        const int ntb  = (wv & 1) * 4;
        const float* bias = gemm ? bC : bB;
        const ushort_t* wsg = ws + (size_t)gemm * 64 * 512;

        f32x4 acc[2][4];
        #pragma unroll
        for (int n = 0; n < 4; ++n) {
            float bv = bias[(ntb + n) * 16 + lr];
            #pragma unroll
            for (int mt = 0; mt < 2; ++mt)
                acc[mt][n] = (f32x4){bv, bv, bv, bv};
        }

        #pragma unroll
        for (int kt = 0; kt < 4; ++kt) {
            bf16x8 ahi[2], alo[2];
            #pragma unroll
            for (int mt = 0; mt < 2; ++mt) {
                ahi[mt] = __builtin_bit_cast(bf16x8,
                    *(const ushort8*)(&xn_hi[mt * 16 + lr][kt * 32 + lg * 8]));
                alo[mt] = __builtin_bit_cast(bf16x8,
                    *(const ushort8*)(&xn_lo[mt * 16 + lr][kt * 32 + lg * 8]));
            }
            #pragma unroll
            for (int n = 0; n < 4; ++n) {
                const int nt = ntb + n;
                const ushort_t* fb = wsg + (size_t)(kt * 8 + nt) * 512 + (size_t)l * 8;
                bf16x8 bhi = __builtin_bit_cast(bf16x8, *(const ushort8*)fb);
                bf16x8 blo = __builtin_bit_cast(bf16x8, *(const ushort8*)(fb + 32 * 512));
                #pragma unroll
                for (int mt = 0; mt < 2; ++mt) {
                    acc[mt][n] = __builtin_amdgcn_mfma_f32_16x16x32_bf16(alo[mt], blo, acc[mt][n], 0, 0, 0);
                    acc[mt][n] = __builtin_amdgcn_mfma_f32_16x16x32_bf16(ahi[mt], blo, acc[mt][n], 0, 0, 0);
                    acc[mt][n] = __builtin_amdgcn_mfma_f32_16x16x32_bf16(alo[mt], bhi, acc[mt][n], 0, 0, 0);
                    acc[mt][n] = __builtin_amdgcn_mfma_f32_16x16x32_bf16(ahi[mt], bhi, acc[mt][n], 0, 0, 0);
                }
            }
        }

        float (*dst)[LSTR] = gemm ? ct_lds : bt_lds;
        #pragma unroll
        for (int mt = 0; mt < 2; ++mt)
            #pragma unroll
            for (int n = 0; n < 4; ++n)
                #pragma unroll
                for (int j = 0; j < 4; ++j)
                    dst[mt * 16 + lg * 4 + j][(ntb + n) * 16 + lr] = acc[mt][n][j];
    }
    __syncthreads();

    // ============ Phase 3: scan h_t = e^A h_{t-1} + Bt; y = Ct*h ============
    // y 3-way split (rep error 2^-24 |y|) into xn_hi / xn_lo / y3_lds.
    if (tid < Dn) {
        const int c = tid;
        const float dec = expf(A[c]);
        float h = 0.f;
        #pragma unroll
        for (int t = 0; t < Tn; ++t) {
            h = fmaf(dec, h, bt_lds[t][c]);
            float y = ct_lds[t][c] * h;
            ushort_t y1 = bf16_rne(y);
            float r1 = y - bf16_to_f32(y1);          // exact
            ushort_t y2 = bf16_rne(r1);
            float r2 = r1 - bf16_to_f32(y2);         // exact
            xn_hi[t][c]  = y1;
            xn_lo[t][c]  = y2;
            y3_lds[t][c] = bf16_rne(r2);
        }
    }
    __syncthreads();

    // ============ Phase 4: out = y@Wo + bo + d_seq (MFMA, 5-term) ===========
    // wave w handles ntiles {2w, 2w+1}, both mtiles.
    {
        const ushort_t* wsg = ws + (size_t)2 * 64 * 512;

        f32x4 acc[2][2];
        #pragma unroll
        for (int n = 0; n < 2; ++n) {
            float bv = bo[(wv * 2 + n) * 16 + lr];
            #pragma unroll
            for (int mt = 0; mt < 2; ++mt)
                acc[mt][n] = (f32x4){bv, bv, bv, bv};
        }

        #pragma unroll
        for (int kt = 0; kt < 4; ++kt) {
            bf16x8 a1[2], a2[2], a3[2];
            #pragma unroll
            for (int mt = 0; mt < 2; ++mt) {
                a1[mt] = __builtin_bit_cast(bf16x8,
                    *(const ushort8*)(&xn_hi[mt * 16 + lr][kt * 32 + lg * 8]));
                a2[mt] = __builtin_bit_cast(bf16x8,
                    *(const ushort8*)(&xn_lo[mt * 16 + lr][kt * 32 + lg * 8]));
                a3[mt] = __builtin_bit_cast(bf16x8,
                    *(const ushort8*)(&y3_lds[mt * 16 + lr][kt * 32 + lg * 8]));
            }
            #pragma unroll
            for (int n = 0; n < 2; ++n) {
                const int nt = wv * 2 + n;
                const ushort_t* fb = wsg + (size_t)(kt * 8 + nt) * 512 + (size_t)l * 8;
                bf16x8 bhi = __builtin_bit_cast(bf16x8, *(const ushort8*)fb);
                bf16x8 blo = __builtin_bit_cast(bf16x8, *(const ushort8*)(fb + 32 * 512));
                #pragma unroll
                for (int mt = 0; mt < 2; ++mt) {
                    acc[mt][n] = __builtin_amdgcn_mfma_f32_16x16x32_bf16(a3[mt], bhi, acc[mt][n], 0, 0, 0);
                    acc[mt][n] = __builtin_amdgcn_mfma_f32_16x16x32_bf16(a2[mt], blo, acc[mt][n], 0, 0, 0);
                    acc[mt][n] = __builtin_amdgcn_mfma_f32_16x16x32_bf16(a2[mt], bhi, acc[mt][n], 0, 0, 0);
                    acc[mt][n] = __builtin_amdgcn_mfma_f32_16x16x32_bf16(a1[mt], blo, acc[mt][n], 0, 0, 0);
                    acc[mt][n] = __builtin_amdgcn_mfma_f32_16x16x32_bf16(a1[mt], bhi, acc[mt][n], 0, 0, 0);
                }
            }
        }

        // epilogue: + d_seq residual, store
        #pragma unroll
        for (int mt = 0; mt < 2; ++mt)
            #pragma unroll
            for (int n = 0; n < 2; ++n) {
                const int nt = wv * 2 + n;
                const int col = nt * 16 + lr;
                #pragma unroll
                for (int j = 0; j < 4; ++j) {
                    const int row = mt * 16 + lg * 4 + j;
                    out[base + (size_t)row * HWD + col] = acc[mt][n][j] + d_lds[row][col];
                }
            }
    }
}

extern "C" void kernel_launch(void* const* d_in, const int* in_sizes, int n_in,
                              void* d_out, int out_size, void* d_ws, size_t ws_size,
                              hipStream_t stream) {
    const float* x  = (const float*)d_in[0];
    const float* g1 = (const float*)d_in[1];
    const float* b1 = (const float*)d_in[2];
    const float* g2 = (const float*)d_in[3];
    const float* b2 = (const float*)d_in[4];
    const float* WB = (const float*)d_in[5];
    const float* bB = (const float*)d_in[6];
    const float* WC = (const float*)d_in[7];
    const float* bC = (const float*)d_in[8];
    const float* Wo = (const float*)d_in[9];
    const float* bo = (const float*)d_in[10];
    const float* A  = (const float*)d_in[11];
    float* out = (float*)d_out;
    ushort_t* wsp = (ushort_t*)d_ws;   // needs 192 KiB

    hipLaunchKernelGGL(prep_weights, dim3(24), dim3(256), 0, stream, WB, WC, Wo, wsp);
    hipLaunchKernelGGL(gmamba_fused, dim3(Bn * Hn * Wn), dim3(256), 0, stream,
                       x, g1, b1, g2, b2, bB, bC, bo, A, wsp, out);
}

// Round 14
// 135.232 us; speedup vs baseline: 1.5162x; 1.0311x over previous
//
#include <hip/hip_runtime.h>
#include <math.h>

// Problem constants (B,T,H,W,D) = (8,32,16,16,128)
#define Bn 8
#define Tn 32
#define Hn 16
#define Wn 16
#define Dn 128
#define HWD (Hn * Wn * Dn)      // 32768 floats between consecutive t
#define LSTR 132                // fp32 LDS row stride
#define HSTR 136                // bf16 LDS row stride (136*2B = 272B = 17*16B)
#define EPSV 1e-5f

typedef __bf16 bf16x8 __attribute__((ext_vector_type(8)));
typedef float f32x4 __attribute__((ext_vector_type(4)));
typedef unsigned short ushort8 __attribute__((ext_vector_type(8)));
typedef unsigned int uint4v __attribute__((ext_vector_type(4)));
typedef unsigned short ushort_t;

__device__ __forceinline__ ushort_t bf16_rne(float f) {
    unsigned u = __builtin_bit_cast(unsigned, f);
    unsigned r = u + 0x7FFFu + ((u >> 16) & 1u);
    return (ushort_t)(r >> 16);
}
__device__ __forceinline__ float bf16_to_f32(ushort_t h) {
    return __builtin_bit_cast(float, (unsigned)h << 16);
}

// ===================== Pre-pass: weights -> MFMA B-fragment layout ==========
// ws layout (ushort units): frag index = w*64 + half*32 + kt*8 + nt; frag =
// 512 ushorts; element j of lane l = W[kt*32 + (l>>4)*8 + j][nt*16 + (l&15)],
// hi (half=0) or lo (half=1) bf16 limb.  w - whi - wlo error <= 2^-16 |w|.
__global__ void prep_weights(const float* __restrict__ WB,
                             const float* __restrict__ WC,
                             const float* __restrict__ Wo,
                             ushort_t* __restrict__ ws)
{
    const int tg = blockIdx.x * 256 + threadIdx.x;   // 0..6143
    const int l  = tg & 63;
    const int f  = tg >> 6;                          // 0..95 = (w, kt, nt)
    const int nt = f & 7;
    const int kt = (f >> 3) & 3;
    const int w  = f >> 5;                           // 0,1,2
    const float* W = (w == 0) ? WB : (w == 1) ? WC : Wo;

    const int row0 = kt * 32 + (l >> 4) * 8;
    const int col  = nt * 16 + (l & 15);

    ushort_t hi[8], lo[8];
    #pragma unroll
    for (int j = 0; j < 8; ++j) {
        float v = W[(size_t)(row0 + j) * Dn + col];
        ushort_t h = bf16_rne(v);
        hi[j] = h;
        lo[j] = bf16_rne(v - bf16_to_f32(h));
    }
    ushort8 vh = {hi[0],hi[1],hi[2],hi[3],hi[4],hi[5],hi[6],hi[7]};
    ushort8 vl = {lo[0],lo[1],lo[2],lo[3],lo[4],lo[5],lo[6],lo[7]};
    size_t hioff = ((size_t)(w * 64 + kt * 8 + nt)) * 512 + (size_t)l * 8;
    size_t looff = ((size_t)(w * 64 + 32 + kt * 8 + nt)) * 512 + (size_t)l * 8;
    *(ushort8*)(ws + hioff) = vh;
    *(ushort8*)(ws + looff) = vl;
}

// ===================== Main fused kernel ====================================
// LDS budget: xn (17.4K) + bt (16.9K) + ct (16.9K) = 51.2 KiB -> 3 blocks/CU.
// y's 3rd limb lives in ct_lds's own slots (race-free: column c is owned by
// scan-thread c; read-before-write in program order).
__launch_bounds__(256, 3)
__global__ void gmamba_fused(const float* __restrict__ x,
                             const float* __restrict__ g1, const float* __restrict__ b1,
                             const float* __restrict__ g2, const float* __restrict__ b2,
                             const float* __restrict__ bB,
                             const float* __restrict__ bC,
                             const float* __restrict__ bo,
                             const float* __restrict__ A,
                             const ushort_t* __restrict__ ws,
                             float* __restrict__ out)
{
    __shared__ __align__(16) float bt_lds[Tn][LSTR];     // Bt (scan input)
    __shared__ __align__(16) float ct_lds[Tn][LSTR];     // Ct, then y3 (low16)
    __shared__ __align__(16) ushort_t xn_hi[Tn][HSTR];   // xn hi limb, later y1
    __shared__ __align__(16) ushort_t xn_lo[Tn][HSTR];   // xn lo limb, later y2

    const int tid = threadIdx.x;
    const int s   = blockIdx.x;          // (b, h*W+w)
    const int b   = s >> 8;
    const int hw  = s & 255;
    const size_t base = (size_t)b * Tn * HWD + (size_t)hw * Dn;

    // ============ Phase 1: d_seq + LN1 + LN2 -> xn (bf16 hi/lo in LDS) ======
    // d_seq is NOT stored; the epilogue recomputes it from x (L3-resident,
    // bit-identical fp32 subtraction).
    {
        const int row = tid >> 3;        // t
        const int sub = tid & 7;
        const int c0  = sub * 16;

        float d[16];
        {
            const float* xr = x + base + (size_t)row * HWD + c0;
            float4 a0 = *(const float4*)(xr + 0);
            float4 a1 = *(const float4*)(xr + 4);
            float4 a2 = *(const float4*)(xr + 8);
            float4 a3 = *(const float4*)(xr + 12);
            if (row > 0) {
                const float* xp = xr - HWD;
                float4 p0 = *(const float4*)(xp + 0);
                float4 p1 = *(const float4*)(xp + 4);
                float4 p2 = *(const float4*)(xp + 8);
                float4 p3 = *(const float4*)(xp + 12);
                d[0]=a0.x-p0.x; d[1]=a0.y-p0.y; d[2]=a0.z-p0.z; d[3]=a0.w-p0.w;
                d[4]=a1.x-p1.x; d[5]=a1.y-p1.y; d[6]=a1.z-p1.z; d[7]=a1.w-p1.w;
                d[8]=a2.x-p2.x; d[9]=a2.y-p2.y; d[10]=a2.z-p2.z; d[11]=a2.w-p2.w;
                d[12]=a3.x-p3.x; d[13]=a3.y-p3.y; d[14]=a3.z-p3.z; d[15]=a3.w-p3.w;
            } else {
                #pragma unroll
                for (int i = 0; i < 16; ++i) d[i] = 0.f;
            }
        }

        float sum = 0.f, ss = 0.f;
        #pragma unroll
        for (int i = 0; i < 16; ++i) { sum += d[i]; ss += d[i] * d[i]; }
        #pragma unroll
        for (int m = 1; m < 8; m <<= 1) {
            sum += __shfl_xor(sum, m);
            ss  += __shfl_xor(ss,  m);
        }
        float mu1 = sum * (1.f / 128.f);
        float rs1 = rsqrtf(ss * (1.f / 128.f) - mu1 * mu1 + EPSV);

        float dn[16];
        #pragma unroll
        for (int i = 0; i < 16; ++i)
            dn[i] = fmaf((d[i] - mu1) * rs1, g1[c0 + i], b1[c0 + i]);

        float sum2 = 0.f, ss2 = 0.f;
        #pragma unroll
        for (int i = 0; i < 16; ++i) { sum2 += dn[i]; ss2 += dn[i] * dn[i]; }
        #pragma unroll
        for (int m = 1; m < 8; m <<= 1) {
            sum2 += __shfl_xor(sum2, m);
            ss2  += __shfl_xor(ss2,  m);
        }
        float mu2 = sum2 * (1.f / 128.f);
        float rs2 = rsqrtf(ss2 * (1.f / 128.f) - mu2 * mu2 + EPSV);

        ushort_t hi[16], lo[16];
        #pragma unroll
        for (int i = 0; i < 16; ++i) {
            float v = fmaf((dn[i] - mu2) * rs2, g2[c0 + i], b2[c0 + i]);
            ushort_t h = bf16_rne(v);
            hi[i] = h;
            lo[i] = bf16_rne(v - bf16_to_f32(h));
        }
        ushort8 h0 = {hi[0],hi[1],hi[2],hi[3],hi[4],hi[5],hi[6],hi[7]};
        ushort8 h1 = {hi[8],hi[9],hi[10],hi[11],hi[12],hi[13],hi[14],hi[15]};
        ushort8 l0 = {lo[0],lo[1],lo[2],lo[3],lo[4],lo[5],lo[6],lo[7]};
        ushort8 l1 = {lo[8],lo[9],lo[10],lo[11],lo[12],lo[13],lo[14],lo[15]};
        *(ushort8*)(&xn_hi[row][c0])     = h0;
        *(ushort8*)(&xn_hi[row][c0 + 8]) = h1;
        *(ushort8*)(&xn_lo[row][c0])     = l0;
        *(ushort8*)(&xn_lo[row][c0 + 8]) = l1;
    }
    __syncthreads();

    const int wv = tid >> 6;     // wave 0..3
    const int l  = tid & 63;
    const int lr = l & 15;       // A-row / B-col / C-col
    const int lg = l >> 4;       // k-group; C row-group

    // ============ Phase 2: Bt = xn@WB + bB ; Ct = xn@WC + bC (MFMA, 4-term) =
    // wave 0: WB ntiles 0-3; wave 1: WB 4-7; wave 2: WC 0-3; wave 3: WC 4-7.
    {
        const int gemm = wv >> 1;
        const int ntb  = (wv & 1) * 4;
        const float* bias = gemm ? bC : bB;
        const ushort_t* wsg = ws + (size_t)gemm * 64 * 512;

        f32x4 acc[2][4];
        #pragma unroll
        for (int n = 0; n < 4; ++n) {
            float bv = bias[(ntb + n) * 16 + lr];
            #pragma unroll
            for (int mt = 0; mt < 2; ++mt)
                acc[mt][n] = (f32x4){bv, bv, bv, bv};
        }

        #pragma unroll
        for (int kt = 0; kt < 4; ++kt) {
            bf16x8 ahi[2], alo[2];
            #pragma unroll
            for (int mt = 0; mt < 2; ++mt) {
                ahi[mt] = __builtin_bit_cast(bf16x8,
                    *(const ushort8*)(&xn_hi[mt * 16 + lr][kt * 32 + lg * 8]));
                alo[mt] = __builtin_bit_cast(bf16x8,
                    *(const ushort8*)(&xn_lo[mt * 16 + lr][kt * 32 + lg * 8]));
            }
            #pragma unroll
            for (int n = 0; n < 4; ++n) {
                const int nt = ntb + n;
                const ushort_t* fb = wsg + (size_t)(kt * 8 + nt) * 512 + (size_t)l * 8;
                bf16x8 bhi = __builtin_bit_cast(bf16x8, *(const ushort8*)fb);
                bf16x8 blo = __builtin_bit_cast(bf16x8, *(const ushort8*)(fb + 32 * 512));
                #pragma unroll
                for (int mt = 0; mt < 2; ++mt) {
                    acc[mt][n] = __builtin_amdgcn_mfma_f32_16x16x32_bf16(alo[mt], blo, acc[mt][n], 0, 0, 0);
                    acc[mt][n] = __builtin_amdgcn_mfma_f32_16x16x32_bf16(ahi[mt], blo, acc[mt][n], 0, 0, 0);
                    acc[mt][n] = __builtin_amdgcn_mfma_f32_16x16x32_bf16(alo[mt], bhi, acc[mt][n], 0, 0, 0);
                    acc[mt][n] = __builtin_amdgcn_mfma_f32_16x16x32_bf16(ahi[mt], bhi, acc[mt][n], 0, 0, 0);
                }
            }
        }

        float (*dst)[LSTR] = gemm ? ct_lds : bt_lds;
        #pragma unroll
        for (int mt = 0; mt < 2; ++mt)
            #pragma unroll
            for (int n = 0; n < 4; ++n)
                #pragma unroll
                for (int j = 0; j < 4; ++j)
                    dst[mt * 16 + lg * 4 + j][(ntb + n) * 16 + lr] = acc[mt][n][j];
    }
    __syncthreads();

    // ============ Phase 3: scan h_t = e^A h_{t-1} + Bt; y = Ct*h ============
    // y 3-limb split (rep error 2^-24 |y|): y1,y2 -> xn_hi/xn_lo; y3 stored
    // bit-cast into ct_lds[t][c] AFTER Ct is consumed (same thread, same slot
    // -> no race; column c untouched by any other thread).
    if (tid < Dn) {
        const int c = tid;
        const float dec = expf(A[c]);
        float h = 0.f;
        #pragma unroll
        for (int t = 0; t < Tn; ++t) {
            h = fmaf(dec, h, bt_lds[t][c]);
            float y = ct_lds[t][c] * h;
            ushort_t y1 = bf16_rne(y);
            float r1 = y - bf16_to_f32(y1);          // exact
            ushort_t y2 = bf16_rne(r1);
            float r2 = r1 - bf16_to_f32(y2);         // exact
            xn_hi[t][c] = y1;
            xn_lo[t][c] = y2;
            ct_lds[t][c] = __builtin_bit_cast(float, (unsigned)bf16_rne(r2));
        }
    }
    __syncthreads();

    // ============ Phase 4: out = y@Wo + bo + d_seq (MFMA, 5-term) ===========
    // wave w handles ntiles {2w, 2w+1}, both mtiles.  a3 (y3) is unpacked
    // from ct_lds low halves (2 x float4 read + 4 packs per fragment).
    {
        const ushort_t* wsg = ws + (size_t)2 * 64 * 512;

        f32x4 acc[2][2];
        #pragma unroll
        for (int n = 0; n < 2; ++n) {
            float bv = bo[(wv * 2 + n) * 16 + lr];
            #pragma unroll
            for (int mt = 0; mt < 2; ++mt)
                acc[mt][n] = (f32x4){bv, bv, bv, bv};
        }

        #pragma unroll
        for (int kt = 0; kt < 4; ++kt) {
            bf16x8 a1[2], a2[2], a3[2];
            #pragma unroll
            for (int mt = 0; mt < 2; ++mt) {
                const int row = mt * 16 + lr;
                const int cb  = kt * 32 + lg * 8;
                a1[mt] = __builtin_bit_cast(bf16x8,
                    *(const ushort8*)(&xn_hi[row][cb]));
                a2[mt] = __builtin_bit_cast(bf16x8,
                    *(const ushort8*)(&xn_lo[row][cb]));
                float4 q0 = *(const float4*)(&ct_lds[row][cb]);
                float4 q1 = *(const float4*)(&ct_lds[row][cb + 4]);
                uint4v pk;
                pk[0] = (__builtin_bit_cast(unsigned, q0.x) & 0xFFFFu) |
                        (__builtin_bit_cast(unsigned, q0.y) << 16);
                pk[1] = (__builtin_bit_cast(unsigned, q0.z) & 0xFFFFu) |
                        (__builtin_bit_cast(unsigned, q0.w) << 16);
                pk[2] = (__builtin_bit_cast(unsigned, q1.x) & 0xFFFFu) |
                        (__builtin_bit_cast(unsigned, q1.y) << 16);
                pk[3] = (__builtin_bit_cast(unsigned, q1.z) & 0xFFFFu) |
                        (__builtin_bit_cast(unsigned, q1.w) << 16);
                a3[mt] = __builtin_bit_cast(bf16x8, pk);
            }
            #pragma unroll
            for (int n = 0; n < 2; ++n) {
                const int nt = wv * 2 + n;
                const ushort_t* fb = wsg + (size_t)(kt * 8 + nt) * 512 + (size_t)l * 8;
                bf16x8 bhi = __builtin_bit_cast(bf16x8, *(const ushort8*)fb);
                bf16x8 blo = __builtin_bit_cast(bf16x8, *(const ushort8*)(fb + 32 * 512));
                #pragma unroll
                for (int mt = 0; mt < 2; ++mt) {
                    acc[mt][n] = __builtin_amdgcn_mfma_f32_16x16x32_bf16(a3[mt], bhi, acc[mt][n], 0, 0, 0);
                    acc[mt][n] = __builtin_amdgcn_mfma_f32_16x16x32_bf16(a2[mt], blo, acc[mt][n], 0, 0, 0);
                    acc[mt][n] = __builtin_amdgcn_mfma_f32_16x16x32_bf16(a2[mt], bhi, acc[mt][n], 0, 0, 0);
                    acc[mt][n] = __builtin_amdgcn_mfma_f32_16x16x32_bf16(a1[mt], blo, acc[mt][n], 0, 0, 0);
                    acc[mt][n] = __builtin_amdgcn_mfma_f32_16x16x32_bf16(a1[mt], bhi, acc[mt][n], 0, 0, 0);
                }
            }
        }

        // epilogue: + d_seq residual recomputed from x, store
        #pragma unroll
        for (int mt = 0; mt < 2; ++mt)
            #pragma unroll
            for (int n = 0; n < 2; ++n) {
                const int col = (wv * 2 + n) * 16 + lr;
                #pragma unroll
                for (int j = 0; j < 4; ++j) {
                    const int row = mt * 16 + lg * 4 + j;
                    float dd = 0.f;
                    if (row > 0) {
                        const float* xp = x + base + (size_t)row * HWD + col;
                        dd = xp[0] - xp[-(int)HWD];
                    }
                    out[base + (size_t)row * HWD + col] = acc[mt][n][j] + dd;
                }
            }
    }
}

extern "C" void kernel_launch(void* const* d_in, const int* in_sizes, int n_in,
                              void* d_out, int out_size, void* d_ws, size_t ws_size,
                              hipStream_t stream) {
    const float* x  = (const float*)d_in[0];
    const float* g1 = (const float*)d_in[1];
    const float* b1 = (const float*)d_in[2];
    const float* g2 = (const float*)d_in[3];
    const float* b2 = (const float*)d_in[4];
    const float* WB = (const float*)d_in[5];
    const float* bB = (const float*)d_in[6];
    const float* WC = (const float*)d_in[7];
    const float* bC = (const float*)d_in[8];
    const float* Wo = (const float*)d_in[9];
    const float* bo = (const float*)d_in[10];
    const float* A  = (const float*)d_in[11];
    float* out = (float*)d_out;
    ushort_t* wsp = (ushort_t*)d_ws;   // needs 192 KiB

    hipLaunchKernelGGL(prep_weights, dim3(24), dim3(256), 0, stream, WB, WC, Wo, wsp);
    hipLaunchKernelGGL(gmamba_fused, dim3(Bn * Hn * Wn), dim3(256), 0, stream,
                       x, g1, b1, g2, b2, bB, bC, bo, A, wsp, out);
}